// Round 13
// baseline (1088.782 us; speedup 1.0000x reference)
//
#include <hip/hip_runtime.h>
#include <hip/hip_bf16.h>
#include <stdint.h>

// Problem constants
#define B_   64
#define S_   200
#define H_   128
#define V_   20000
#define M_   12800      // B_*S_
#define NPAD 20224      // 158*128
#define NBN  158        // N blocks of 128
#define NBMD 200        // M blocks of 64 (direct GEMM)
#define NWGD 31600      // NBN*NBMD (== 8*3950)

// ws offsets (bytes) — total ~13.7 MB
#define WS_A      0u          // A1_bf16 [12800][128]      3,276,800 B
#define WS_FCW    3276800u    // W1_bf16 [20224][128]      5,177,344 B
#define WS_U      8454144u    // U [64][20224] f32         5,177,344 B
#define WS_RSUM   13631488u   // rowsum [12800] f32           51,200 B
#define WS_WTIH   13682688u   // W_ih^T [128][128] f32        65,536 B

// scratch inside the y region of d_out (float offsets) — overwritten by final pass
#define XP_OFF    0
#define HOUT_OFF  2000000
#define PART_OFF  4000000          // [NBN][12800] partial exp-sums
#define OUTPU_OFF 256000000ll      // real output 1 (out_pu)

typedef __attribute__((ext_vector_type(8))) __bf16 bf16x8;
typedef __attribute__((ext_vector_type(4))) float  f32x4;

// ---------------- prep: W_ih transpose ----------------
__global__ __launch_bounds__(128)
void prep_wt(const float* __restrict__ w_ih, float* __restrict__ wt) {
  int bid = blockIdx.x, t = threadIdx.x;        // grid 128 x 128
  wt[bid * 128 + t] = w_ih[t * 128 + bid];      // wt[k][j] = W_ih[j][k]
}

// ---------------- K1: x_proj, 16 rows/block ----------------
__global__ __launch_bounds__(128)
void xproj_k(const int* __restrict__ poi, const float* __restrict__ emb,
             const float* __restrict__ wt_ih, const float* __restrict__ b_ih,
             const float* __restrict__ b_hh, float* __restrict__ xp) {
  __shared__ float xs[16][128];
  int j = threadIdx.x;
  int m0 = blockIdx.x * 16;                          // grid 800 x 128
#pragma unroll
  for (int i = 0; i < 16; ++i)
    xs[i][j] = emb[(long)poi[m0 + i] * 128 + j];
  __syncthreads();
  float bias = b_ih[j] + b_hh[j];
  float acc[16];
#pragma unroll
  for (int i = 0; i < 16; ++i) acc[i] = bias;
  for (int kq = 0; kq < 32; ++kq) {
    float w0 = wt_ih[(4 * kq + 0) * 128 + j];
    float w1 = wt_ih[(4 * kq + 1) * 128 + j];
    float w2 = wt_ih[(4 * kq + 2) * 128 + j];
    float w3 = wt_ih[(4 * kq + 3) * 128 + j];
#pragma unroll
    for (int i = 0; i < 16; ++i) {
      float4 xv = *(const float4*)&xs[i][4 * kq];
      acc[i] = fmaf(xv.x, w0, acc[i]);
      acc[i] = fmaf(xv.y, w1, acc[i]);
      acc[i] = fmaf(xv.z, w2, acc[i]);
      acc[i] = fmaf(xv.w, w3, acc[i]);
    }
  }
#pragma unroll
  for (int i = 0; i < 16; ++i)
    xp[(long)(m0 + i) * 128 + j] = acc[i];
}

// ---------------- fused: rnn (blk 0..63) + prep_w1 (64..221) + user (222..853) ----
__global__ __launch_bounds__(256)
void fused_pre(const float* __restrict__ xp, const float* __restrict__ w_hh,
               float* __restrict__ hout,
               const float* __restrict__ fcW, __hip_bfloat16* __restrict__ w1,
               const int* __restrict__ auser, const float* __restrict__ userW,
               const float* __restrict__ fcb, float* __restrict__ U) {
  __shared__ float smem_u[8][128];
  int blk = blockIdx.x;
  int t = threadIdx.x;

  if (blk < 64) {
    int b = blk, j = t & 127;
    float* hs = (float*)smem_u;                      // hs[2][128]
    float w[128];
#pragma unroll
    for (int k = 0; k < 128; ++k) w[k] = w_hh[j * 128 + k];
    hs[j] = 0.f;
    __syncthreads();
    int cur = 0;
    for (int tt = 0; tt < S_; ++tt) {
      float x0 = xp[((long)b * S_ + tt) * 128 + j];
      const float4* hp4 = (const float4*)(hs + cur * 128);
      float a0 = 0.f, a1 = 0.f, a2 = 0.f, a3 = 0.f;
#pragma unroll
      for (int k = 0; k < 8; ++k) {
        float4 v0 = hp4[k], v1 = hp4[k + 8], v2 = hp4[k + 16], v3 = hp4[k + 24];
        a0 = fmaf(v0.x, w[4 * k + 0], a0); a0 = fmaf(v0.y, w[4 * k + 1], a0);
        a0 = fmaf(v0.z, w[4 * k + 2], a0); a0 = fmaf(v0.w, w[4 * k + 3], a0);
        a1 = fmaf(v1.x, w[32 + 4 * k + 0], a1); a1 = fmaf(v1.y, w[32 + 4 * k + 1], a1);
        a1 = fmaf(v1.z, w[32 + 4 * k + 2], a1); a1 = fmaf(v1.w, w[32 + 4 * k + 3], a1);
        a2 = fmaf(v2.x, w[64 + 4 * k + 0], a2); a2 = fmaf(v2.y, w[64 + 4 * k + 1], a2);
        a2 = fmaf(v2.z, w[64 + 4 * k + 2], a2); a2 = fmaf(v2.w, w[64 + 4 * k + 3], a2);
        a3 = fmaf(v3.x, w[96 + 4 * k + 0], a3); a3 = fmaf(v3.y, w[96 + 4 * k + 1], a3);
        a3 = fmaf(v3.z, w[96 + 4 * k + 2], a3); a3 = fmaf(v3.w, w[96 + 4 * k + 3], a3);
      }
      float hn = tanhf(x0 + ((a0 + a1) + (a2 + a3)));
      hs[(cur ^ 1) * 128 + j] = hn;
      hout[((long)b * S_ + tt) * 128 + j] = hn;
      cur ^= 1;
      __syncthreads();
    }
  } else if (blk < 222) {
    int row = (blk - 64) * 128 + (t >> 1);
    int c0 = (t & 1) * 64;
    const float* src = fcW + (long)row * 256 + c0;
    __hip_bfloat16* dst = w1 + (long)row * 128 + c0;
    bool valid = row < V_;
#pragma unroll
    for (int q = 0; q < 8; ++q) {
      float4 v0, v1;
      if (valid) { v0 = *(const float4*)(src + q * 8); v1 = *(const float4*)(src + q * 8 + 4); }
      else { v0 = make_float4(0.f, 0.f, 0.f, 0.f); v1 = v0; }
      ushort4 p0, p1;
      p0.x = __bfloat16_as_ushort(__float2bfloat16(v0.x));
      p0.y = __bfloat16_as_ushort(__float2bfloat16(v0.y));
      p0.z = __bfloat16_as_ushort(__float2bfloat16(v0.z));
      p0.w = __bfloat16_as_ushort(__float2bfloat16(v0.w));
      p1.x = __bfloat16_as_ushort(__float2bfloat16(v1.x));
      p1.y = __bfloat16_as_ushort(__float2bfloat16(v1.y));
      p1.z = __bfloat16_as_ushort(__float2bfloat16(v1.z));
      p1.w = __bfloat16_as_ushort(__float2bfloat16(v1.w));
      *(ushort4*)(dst + q * 8)     = p0;
      *(ushort4*)(dst + q * 8 + 4) = p1;
    }
  } else {
    int idx = blk - 222;
    int cb = idx % 79, bgrp = idx / 79;
    int c = cb * 256 + t;
    int b0 = bgrp * 8;
    for (int i = t; i < 8 * 128; i += 256) {
      int bb = i >> 7, kk = i & 127;
      smem_u[bb][kk] = userW[(long)auser[b0 + bb] * 128 + kk];
    }
    __syncthreads();
    float acc[8];
#pragma unroll
    for (int bb = 0; bb < 8; ++bb) acc[bb] = 0.f;
    if (c < V_) {
      const float* w2 = fcW + (long)c * 256 + 128;
      for (int kq = 0; kq < 32; ++kq) {
        float4 wv = *(const float4*)(w2 + 4 * kq);
#pragma unroll
        for (int bb = 0; bb < 8; ++bb) {
          float4 uv = *(const float4*)&smem_u[bb][4 * kq];
          acc[bb] = fmaf(wv.x, uv.x, acc[bb]);
          acc[bb] = fmaf(wv.y, uv.y, acc[bb]);
          acc[bb] = fmaf(wv.z, uv.z, acc[bb]);
          acc[bb] = fmaf(wv.w, uv.w, acc[bb]);
        }
      }
      float base = fcb[c];
#pragma unroll
      for (int bb = 0; bb < 8; ++bb)
        U[(long)(b0 + bb) * NPAD + c] = base + acc[bb];
    } else {
#pragma unroll
      for (int bb = 0; bb < 8; ++bb)
        U[(long)(b0 + bb) * NPAD + c] = -1e30f;
    }
  }
}

// ---------------- K3: decay attention (r8/r11 best shape) ----------------
__global__ __launch_bounds__(128)
void attn_k(const float* __restrict__ ts, const float* __restrict__ loc,
            const float* __restrict__ hout, const int* __restrict__ auser,
            const float* __restrict__ userW, float* __restrict__ outpu,
            __hip_bfloat16* __restrict__ Abf) {
  int i = blockIdx.x, b = blockIdx.y, h = threadIdx.x;   // grid (200,64) x 128
  __shared__ float wl[128];
  const float OMEGA = 7.27220521664304e-05f;             // 2*pi/86400
  float ti = ts[b * S_ + i];
  float lx = loc[(b * S_ + i) * 2 + 0];
  float ly = loc[(b * S_ + i) * 2 + 1];
  float acc = 0.f, sw = 0.f;
  for (int jc = 0; jc <= i; jc += 128) {
    int j = jc + h;
    float wj = 0.f;
    if (j <= i) {
      float dt = fmaxf(ti - ts[b * S_ + j], 0.f);
      float a = (cosf(dt * OMEGA) + 1.f) * 0.5f * expf(-dt * 0.01f);
      float dx = lx - loc[(b * S_ + j) * 2 + 0];
      float dy = ly - loc[(b * S_ + j) * 2 + 1];
      float dn = sqrtf(dx * dx + dy * dy);
      wj = a * expf(-dn * 100.f) + 1e-10f;
    }
    __syncthreads();
    wl[h] = wj;
    __syncthreads();
    int lim = min(128, i - jc + 1);
    const float* hb = hout + ((long)b * S_ + jc) * 128 + h;
    int jj = 0;
    for (; jj + 4 <= lim; jj += 4) {
      float4 wv4 = *(const float4*)&wl[jj];
      float h0 = hb[(long)(jj + 0) * 128];
      float h1 = hb[(long)(jj + 1) * 128];
      float h2 = hb[(long)(jj + 2) * 128];
      float h3 = hb[(long)(jj + 3) * 128];
      acc = fmaf(wv4.x, h0, acc); sw += wv4.x;
      acc = fmaf(wv4.y, h1, acc); sw += wv4.y;
      acc = fmaf(wv4.z, h2, acc); sw += wv4.z;
      acc = fmaf(wv4.w, h3, acc); sw += wv4.w;
    }
    for (; jj < lim; ++jj) {
      float wv = wl[jj];
      acc = fmaf(wv, hb[(long)jj * 128], acc);
      sw += wv;
    }
  }
  float ow = acc / fmaxf(sw, 1e-10f);
  long m = (long)b * S_ + i;
  float pu = userW[(long)auser[b] * 128 + h];
  outpu[m * 256 + h]       = ow;
  outpu[m * 256 + 128 + h] = pu;
  Abf[m * 128 + h]         = __float2bfloat16(ow);
}

// ---------------- K4/K5: FC GEMM, DIRECT-FROM-L2, 64x128 tile, 5 blocks/CU ----
// No LDS staging / no barriers in the main loop: MFMA fragments loaded straight
// global->VGPR (wave reads 16 rows x 64B = full cache lines; A/B are L2-hot).
// 256 thr / 4 waves (each wave one 64x32 col-slice). LDS = 32KB epilogue buffer.
// logit(r,c) = acc(r,c) + U[r/200][c];  PASS0: rowsum partials;  PASS1: y = exp/rowsum
template <int PASS>
__global__ __launch_bounds__(256, 5)
void gemm_d(const __hip_bfloat16* __restrict__ A,    // [12800][128]
            const __hip_bfloat16* __restrict__ Bw,   // [20224][128]
            const float* __restrict__ Ut,            // [64][20224]
            const float* __restrict__ rowsum,        // [12800] (PASS 1)
            float* __restrict__ part,                 // [NBN][12800] (PASS 0)
            float* __restrict__ y) {                  // [12800][20000] (PASS 1)
  __shared__ __align__(16) float Lf[64 * 128];   // 32 KB

  const int tid  = threadIdx.x;
  const int lane = tid & 63;
  const int wc   = tid >> 6;               // 0..3: N col-slice
  const int g = lane >> 4, lr = lane & 15;

  // bijective XCD swizzle: 31600 = 8*3950 exactly; bn slow, bm fast (r8 best)
  const int orig = blockIdx.x;
  const int nid = (orig & 7) * (NWGD / 8) + (orig >> 3);
  const int bn = nid / NBMD, bm = nid % NBMD;
  const long brow = (long)bm * 64, bcol = (long)bn * 128;

  const char* Ab = (const char*)A + brow * 256;   // row stride 128*2B
  const char* Bb = (const char*)Bw + bcol * 256;

  f32x4 acc[4][2];
#pragma unroll
  for (int mi = 0; mi < 4; ++mi)
#pragma unroll
    for (int ni = 0; ni < 2; ++ni) acc[mi][ni] = (f32x4)(0.f);

#pragma unroll
  for (int kk = 0; kk < 4; ++kk) {
    bf16x8 af[4], bfr[2];
#pragma unroll
    for (int mi = 0; mi < 4; ++mi)
      af[mi] = *(const bf16x8*)(Ab + (long)(mi * 16 + lr) * 256 + (kk * 4 + g) * 16);
#pragma unroll
    for (int ni = 0; ni < 2; ++ni)
      bfr[ni] = *(const bf16x8*)(Bb + (long)(wc * 32 + ni * 16 + lr) * 256 + (kk * 4 + g) * 16);
#pragma unroll
    for (int mi = 0; mi < 4; ++mi)
#pragma unroll
      for (int ni = 0; ni < 2; ++ni)
        acc[mi][ni] = __builtin_amdgcn_mfma_f32_16x16x32_bf16(af[mi], bfr[ni], acc[mi][ni], 0, 0, 0);
  }

  if (PASS == 0) {
#pragma unroll
    for (int mi = 0; mi < 4; ++mi) {
#pragma unroll
      for (int r = 0; r < 4; ++r) {
        long row = brow + mi * 16 + g * 4 + r;
        const float* urow = Ut + (long)(row / S_) * NPAD + bcol;
        float s = 0.f;
#pragma unroll
        for (int ni = 0; ni < 2; ++ni) {
          float u = urow[wc * 32 + ni * 16 + lr];
          s += __expf(acc[mi][ni][r] + u);
        }
#pragma unroll
        for (int off = 1; off < 16; off <<= 1) s += __shfl_xor(s, off);
        if (lr == 0) Lf[wc * 64 + mi * 16 + g * 4 + r] = s;
      }
    }
    __syncthreads();
    if (tid < 64)
      part[(long)bn * M_ + brow + tid] =
          Lf[tid] + Lf[64 + tid] + Lf[128 + tid] + Lf[192 + tid];
  } else {
    if (bcol >= V_) return;                   // fully-OOB N panel (bn==157)
    const bool full = (bcol + 128 <= V_);
#pragma unroll
    for (int mi = 0; mi < 4; ++mi) {
#pragma unroll
      for (int r = 0; r < 4; ++r) {
        int lrow = mi * 16 + g * 4 + r;            // 0..63
        long row = brow + lrow;
        const float* urow = Ut + (long)(row / S_) * NPAD + bcol;
        float inv = 1.0f / rowsum[row];
        int key = ((lrow >> 2) & 3) << 2;          // = g<<2: breaks 4-way conflict
#pragma unroll
        for (int ni = 0; ni < 2; ++ni) {
          int lcol = wc * 32 + ni * 16 + lr;
          Lf[lrow * 128 + (lcol ^ key)] = __expf(acc[mi][ni][r] + urow[lcol]) * inv;
        }
      }
    }
    __syncthreads();
    if (full) {
#pragma unroll
      for (int it = 0; it < 8; ++it) {
        int idx = it * 256 + tid;             // 0..2047 f32x4 slots
        int lrow = idx >> 5, c4 = idx & 31;
        int key = ((lrow >> 2) & 3) << 2;
        f32x4 v = *(const f32x4*)(Lf + lrow * 128 + ((c4 * 4) ^ key));
        __builtin_nontemporal_store(v,
            (f32x4*)(y + (brow + lrow) * (long)V_ + bcol + c4 * 4));
      }
    } else {
#pragma unroll
      for (int it = 0; it < 8; ++it) {
        int idx = it * 256 + tid;
        int lrow = idx >> 5, c4 = idx & 31;
        int key = ((lrow >> 2) & 3) << 2;
        const float* src = Lf + lrow * 128 + ((c4 * 4) ^ key);
        long row = brow + lrow;
#pragma unroll
        for (int e = 0; e < 4; ++e) {
          int col = (int)bcol + c4 * 4 + e;
          if (col < V_) y[row * (long)V_ + col] = src[e];
        }
      }
    }
  }
}

__global__ void reduce_rows(const float* __restrict__ part, float* __restrict__ rowsum) {
  int m = blockIdx.x * 256 + threadIdx.x;            // grid 50 x 256
  if (m < M_) {
    float s = 0.f;
    for (int bn = 0; bn < NBN; ++bn) s += part[(long)bn * M_ + m];
    rowsum[m] = fmaxf(s, 1e-30f);
  }
}

// ---------------- launcher ----------------
extern "C" void kernel_launch(void* const* d_in, const int* in_sizes, int n_in,
                              void* d_out, int out_size, void* d_ws, size_t ws_size,
                              hipStream_t stream) {
  const int*   poi   = (const int*)d_in[0];
  // d_in[1] = lengths (all == S, unused)
  const float* ts    = (const float*)d_in[2];
  const float* loc   = (const float*)d_in[3];
  const int*   auser = (const int*)d_in[4];
  const float* embW  = (const float*)d_in[5];
  const float* userW = (const float*)d_in[6];
  const float* w_ih  = (const float*)d_in[7];
  const float* w_hh  = (const float*)d_in[8];
  const float* b_ih  = (const float*)d_in[9];
  const float* b_hh  = (const float*)d_in[10];
  const float* fcW   = (const float*)d_in[11];
  const float* fcb   = (const float*)d_in[12];

  float* out = (float*)d_out;
  char*  ws  = (char*)d_ws;
  __hip_bfloat16* Abf    = (__hip_bfloat16*)(ws + WS_A);
  __hip_bfloat16* w1b    = (__hip_bfloat16*)(ws + WS_FCW);
  float*          Ut     = (float*)(ws + WS_U);
  float*          rowsum = (float*)(ws + WS_RSUM);
  float*          wt_ih  = (float*)(ws + WS_WTIH);

  float* xp    = out + XP_OFF;     // scratch inside y region (overwritten by pass 1)
  float* hout  = out + HOUT_OFF;
  float* part  = out + PART_OFF;
  float* outpu = out + OUTPU_OFF;  // real output 1

  prep_wt<<<dim3(128), dim3(128), 0, stream>>>(w_ih, wt_ih);
  xproj_k<<<dim3(M_ / 16), dim3(128), 0, stream>>>(poi, embW, wt_ih, b_ih, b_hh, xp);
  fused_pre<<<dim3(64 + 158 + 632), dim3(256), 0, stream>>>(
      xp, w_hh, hout, fcW, w1b, auser, userW, fcb, Ut);
  attn_k<<<dim3(S_, B_), dim3(128), 0, stream>>>(ts, loc, hout, auser, userW, outpu, Abf);
  gemm_d<0><<<dim3(NWGD), dim3(256), 0, stream>>>(Abf, w1b, Ut, nullptr, part, nullptr);
  reduce_rows<<<dim3(50), dim3(256), 0, stream>>>(part, rowsum);
  gemm_d<1><<<dim3(NWGD), dim3(256), 0, stream>>>(Abf, w1b, Ut, rowsum, nullptr, out);
}

// Round 14
// 693.584 us; speedup vs baseline: 1.5698x; 1.5698x over previous
//
#include <hip/hip_runtime.h>
#include <hip/hip_bf16.h>
#include <stdint.h>

// Problem constants
#define B_   64
#define S_   200
#define H_   128
#define V_   20000
#define M_   12800      // B_*S_
#define NPAD 20224      // 158*128
#define NBN  158        // N panels of 128 cols
#define NBM64 200       // M blocks of 64 rows
#define NWG64 31600     // NBN*NBM64 (== 8*3950)

// ws offsets (bytes) — total ~13.7 MB
#define WS_A      0u          // A1_bf16 [12800][128]      3,276,800 B
#define WS_FCW    3276800u    // W1_bf16 [20224][128]      5,177,344 B
#define WS_U      8454144u    // U [64][20224] f32         5,177,344 B
#define WS_RSUM   13631488u   // rowsum [12800] f32           51,200 B
#define WS_WTIH   13682688u   // W_ih^T [128][128] f32        65,536 B

// scratch inside the y region of d_out (float offsets) — overwritten by final pass
#define XP_OFF    0
#define HOUT_OFF  2000000
#define PART_OFF  4000000          // [NBN][12800] partial exp-sums
#define OUTPU_OFF 256000000ll      // real output 1 (out_pu)

typedef __attribute__((ext_vector_type(8))) __bf16 bf16x8;
typedef __attribute__((ext_vector_type(4))) float  f32x4;

__device__ __forceinline__ void gll16(const void* g, void* l) {
  __builtin_amdgcn_global_load_lds(
      (const __attribute__((address_space(1))) void*)g,
      (__attribute__((address_space(3))) void*)l, 16, 0, 0);
}

// ---------------- prep: W_ih transpose ----------------
__global__ __launch_bounds__(128)
void prep_wt(const float* __restrict__ w_ih, float* __restrict__ wt) {
  int bid = blockIdx.x, t = threadIdx.x;        // grid 128 x 128
  wt[bid * 128 + t] = w_ih[t * 128 + bid];      // wt[k][j] = W_ih[j][k]
}

// ---------------- K1: x_proj, 16 rows/block ----------------
__global__ __launch_bounds__(128)
void xproj_k(const int* __restrict__ poi, const float* __restrict__ emb,
             const float* __restrict__ wt_ih, const float* __restrict__ b_ih,
             const float* __restrict__ b_hh, float* __restrict__ xp) {
  __shared__ float xs[16][128];
  int j = threadIdx.x;
  int m0 = blockIdx.x * 16;                          // grid 800 x 128
#pragma unroll
  for (int i = 0; i < 16; ++i)
    xs[i][j] = emb[(long)poi[m0 + i] * 128 + j];
  __syncthreads();
  float bias = b_ih[j] + b_hh[j];
  float acc[16];
#pragma unroll
  for (int i = 0; i < 16; ++i) acc[i] = bias;
  for (int kq = 0; kq < 32; ++kq) {
    float w0 = wt_ih[(4 * kq + 0) * 128 + j];
    float w1 = wt_ih[(4 * kq + 1) * 128 + j];
    float w2 = wt_ih[(4 * kq + 2) * 128 + j];
    float w3 = wt_ih[(4 * kq + 3) * 128 + j];
#pragma unroll
    for (int i = 0; i < 16; ++i) {
      float4 xv = *(const float4*)&xs[i][4 * kq];
      acc[i] = fmaf(xv.x, w0, acc[i]);
      acc[i] = fmaf(xv.y, w1, acc[i]);
      acc[i] = fmaf(xv.z, w2, acc[i]);
      acc[i] = fmaf(xv.w, w3, acc[i]);
    }
  }
#pragma unroll
  for (int i = 0; i < 16; ++i)
    xp[(long)(m0 + i) * 128 + j] = acc[i];
}

// ---------------- fused: rnn (blk 0..63) + prep_w1 (64..221) + user (222..853) ----
__global__ __launch_bounds__(256)
void fused_pre(const float* __restrict__ xp, const float* __restrict__ w_hh,
               float* __restrict__ hout,
               const float* __restrict__ fcW, __hip_bfloat16* __restrict__ w1,
               const int* __restrict__ auser, const float* __restrict__ userW,
               const float* __restrict__ fcb, float* __restrict__ U) {
  __shared__ float smem_u[8][128];
  int blk = blockIdx.x;
  int t = threadIdx.x;

  if (blk < 64) {
    int b = blk, j = t & 127;
    float* hs = (float*)smem_u;                      // hs[2][128]
    float w[128];
#pragma unroll
    for (int k = 0; k < 128; ++k) w[k] = w_hh[j * 128 + k];
    hs[j] = 0.f;
    __syncthreads();
    int cur = 0;
    for (int tt = 0; tt < S_; ++tt) {
      float x0 = xp[((long)b * S_ + tt) * 128 + j];
      const float4* hp4 = (const float4*)(hs + cur * 128);
      float a0 = 0.f, a1 = 0.f, a2 = 0.f, a3 = 0.f;
#pragma unroll
      for (int k = 0; k < 8; ++k) {
        float4 v0 = hp4[k], v1 = hp4[k + 8], v2 = hp4[k + 16], v3 = hp4[k + 24];
        a0 = fmaf(v0.x, w[4 * k + 0], a0); a0 = fmaf(v0.y, w[4 * k + 1], a0);
        a0 = fmaf(v0.z, w[4 * k + 2], a0); a0 = fmaf(v0.w, w[4 * k + 3], a0);
        a1 = fmaf(v1.x, w[32 + 4 * k + 0], a1); a1 = fmaf(v1.y, w[32 + 4 * k + 1], a1);
        a1 = fmaf(v1.z, w[32 + 4 * k + 2], a1); a1 = fmaf(v1.w, w[32 + 4 * k + 3], a1);
        a2 = fmaf(v2.x, w[64 + 4 * k + 0], a2); a2 = fmaf(v2.y, w[64 + 4 * k + 1], a2);
        a2 = fmaf(v2.z, w[64 + 4 * k + 2], a2); a2 = fmaf(v2.w, w[64 + 4 * k + 3], a2);
        a3 = fmaf(v3.x, w[96 + 4 * k + 0], a3); a3 = fmaf(v3.y, w[96 + 4 * k + 1], a3);
        a3 = fmaf(v3.z, w[96 + 4 * k + 2], a3); a3 = fmaf(v3.w, w[96 + 4 * k + 3], a3);
      }
      float hn = tanhf(x0 + ((a0 + a1) + (a2 + a3)));
      hs[(cur ^ 1) * 128 + j] = hn;
      hout[((long)b * S_ + tt) * 128 + j] = hn;
      cur ^= 1;
      __syncthreads();
    }
  } else if (blk < 222) {
    int row = (blk - 64) * 128 + (t >> 1);
    int c0 = (t & 1) * 64;
    const float* src = fcW + (long)row * 256 + c0;
    __hip_bfloat16* dst = w1 + (long)row * 128 + c0;
    bool valid = row < V_;
#pragma unroll
    for (int q = 0; q < 8; ++q) {
      float4 v0, v1;
      if (valid) { v0 = *(const float4*)(src + q * 8); v1 = *(const float4*)(src + q * 8 + 4); }
      else { v0 = make_float4(0.f, 0.f, 0.f, 0.f); v1 = v0; }
      ushort4 p0, p1;
      p0.x = __bfloat16_as_ushort(__float2bfloat16(v0.x));
      p0.y = __bfloat16_as_ushort(__float2bfloat16(v0.y));
      p0.z = __bfloat16_as_ushort(__float2bfloat16(v0.z));
      p0.w = __bfloat16_as_ushort(__float2bfloat16(v0.w));
      p1.x = __bfloat16_as_ushort(__float2bfloat16(v1.x));
      p1.y = __bfloat16_as_ushort(__float2bfloat16(v1.y));
      p1.z = __bfloat16_as_ushort(__float2bfloat16(v1.z));
      p1.w = __bfloat16_as_ushort(__float2bfloat16(v1.w));
      *(ushort4*)(dst + q * 8)     = p0;
      *(ushort4*)(dst + q * 8 + 4) = p1;
    }
  } else {
    int idx = blk - 222;
    int cb = idx % 79, bgrp = idx / 79;
    int c = cb * 256 + t;
    int b0 = bgrp * 8;
    for (int i = t; i < 8 * 128; i += 256) {
      int bb = i >> 7, kk = i & 127;
      smem_u[bb][kk] = userW[(long)auser[b0 + bb] * 128 + kk];
    }
    __syncthreads();
    float acc[8];
#pragma unroll
    for (int bb = 0; bb < 8; ++bb) acc[bb] = 0.f;
    if (c < V_) {
      const float* w2 = fcW + (long)c * 256 + 128;
      for (int kq = 0; kq < 32; ++kq) {
        float4 wv = *(const float4*)(w2 + 4 * kq);
#pragma unroll
        for (int bb = 0; bb < 8; ++bb) {
          float4 uv = *(const float4*)&smem_u[bb][4 * kq];
          acc[bb] = fmaf(wv.x, uv.x, acc[bb]);
          acc[bb] = fmaf(wv.y, uv.y, acc[bb]);
          acc[bb] = fmaf(wv.z, uv.z, acc[bb]);
          acc[bb] = fmaf(wv.w, uv.w, acc[bb]);
        }
      }
      float base = fcb[c];
#pragma unroll
      for (int bb = 0; bb < 8; ++bb)
        U[(long)(b0 + bb) * NPAD + c] = base + acc[bb];
    } else {
#pragma unroll
      for (int bb = 0; bb < 8; ++bb)
        U[(long)(b0 + bb) * NPAD + c] = -1e30f;
    }
  }
}

// ---------------- K3: decay attention (r8/r11 best shape) ----------------
__global__ __launch_bounds__(128)
void attn_k(const float* __restrict__ ts, const float* __restrict__ loc,
            const float* __restrict__ hout, const int* __restrict__ auser,
            const float* __restrict__ userW, float* __restrict__ outpu,
            __hip_bfloat16* __restrict__ Abf) {
  int i = blockIdx.x, b = blockIdx.y, h = threadIdx.x;   // grid (200,64) x 128
  __shared__ float wl[128];
  const float OMEGA = 7.27220521664304e-05f;             // 2*pi/86400
  float ti = ts[b * S_ + i];
  float lx = loc[(b * S_ + i) * 2 + 0];
  float ly = loc[(b * S_ + i) * 2 + 1];
  float acc = 0.f, sw = 0.f;
  for (int jc = 0; jc <= i; jc += 128) {
    int j = jc + h;
    float wj = 0.f;
    if (j <= i) {
      float dt = fmaxf(ti - ts[b * S_ + j], 0.f);
      float a = (cosf(dt * OMEGA) + 1.f) * 0.5f * expf(-dt * 0.01f);
      float dx = lx - loc[(b * S_ + j) * 2 + 0];
      float dy = ly - loc[(b * S_ + j) * 2 + 1];
      float dn = sqrtf(dx * dx + dy * dy);
      wj = a * expf(-dn * 100.f) + 1e-10f;
    }
    __syncthreads();
    wl[h] = wj;
    __syncthreads();
    int lim = min(128, i - jc + 1);
    const float* hb = hout + ((long)b * S_ + jc) * 128 + h;
    int jj = 0;
    for (; jj + 4 <= lim; jj += 4) {
      float4 wv4 = *(const float4*)&wl[jj];
      float h0 = hb[(long)(jj + 0) * 128];
      float h1 = hb[(long)(jj + 1) * 128];
      float h2 = hb[(long)(jj + 2) * 128];
      float h3 = hb[(long)(jj + 3) * 128];
      acc = fmaf(wv4.x, h0, acc); sw += wv4.x;
      acc = fmaf(wv4.y, h1, acc); sw += wv4.y;
      acc = fmaf(wv4.z, h2, acc); sw += wv4.z;
      acc = fmaf(wv4.w, h3, acc); sw += wv4.w;
    }
    for (; jj < lim; ++jj) {
      float wv = wl[jj];
      acc = fmaf(wv, hb[(long)jj * 128], acc);
      sw += wv;
    }
  }
  float ow = acc / fmaxf(sw, 1e-10f);
  long m = (long)b * S_ + i;
  float pu = userW[(long)auser[b] * 128 + h];
  outpu[m * 256 + h]       = ow;
  outpu[m * 256 + 128 + h] = pu;
  Abf[m * 128 + h]         = __float2bfloat16(ow);
}

// ---------------- K4/K5: FC GEMM, K=128 one-shot, 64x128 tile, 3 blocks/CU ----
// r11 structure (one-shot LDS stage, swizzled, bn-slow XCD order) with smaller
// M-tile: 48KB LDS -> 3 independent blocks/CU (24 waves) for deeper overlap.
// logit(r,c) = acc(r,c) + U[r/200][c];  PASS0: rowsum partials;  PASS1: y = exp/rowsum
template <int PASS>
__global__ __launch_bounds__(512, 6)
void gemm_fc(const __hip_bfloat16* __restrict__ A,    // [12800][128]
             const __hip_bfloat16* __restrict__ Bw,   // [20224][128]
             const float* __restrict__ Ut,            // [64][20224]
             const float* __restrict__ rowsum,        // [12800] (PASS 1)
             float* __restrict__ part,                 // [NBN][12800] (PASS 0)
             float* __restrict__ y) {                  // [12800][20000] (PASS 1)
  __shared__ __align__(16) char smem[49152];     // As 16K | Bs 32K ; lbuf(32K) reuse
  __shared__ float rsum4[4][64];
  char* AsB = smem;
  char* BsB = smem + 16384;
  float* lbuf = (float*)smem;                    // [64][128] f32 (PASS 1 epilogue)

  const int tid  = threadIdx.x;
  const int lane = tid & 63;
  const int wid  = tid >> 6;               // 0..7
  const int wr = wid >> 2, wc = wid & 3;   // 2(M:32) x 4(N:32); wave tile 32x32
  const int g = lane >> 4, lr = lane & 15;

  // bijective XCD swizzle: 31600 = 8*3950 exactly; bn slow, bm fast (r8 best)
  const int orig = blockIdx.x;
  const int nid = (orig & 7) * (NWG64 / 8) + (orig >> 3);
  const int bn = nid / NBM64, bm = nid % NBM64;
  const long brow = (long)bm * 64, bcol = (long)bn * 128;

  const char* Ab = (const char*)A + brow * 256;   // row stride 128*2B
  const char* Bb = (const char*)Bw + bcol * 256;

  // one-shot stage: 16 KB A + 32 KB B. LDS dest linear; global src pre-swizzled
  // (w ^= row&7 on 16B units) so swizzled ds_reads are conflict-free.
#pragma unroll
  for (int i = 0; i < 2; ++i) {
    int ci = i * 512 + tid;                  // 0..1023 16B-chunks (A, 64 rows)
    int row = ci >> 4;
    int w = (ci & 15) ^ (row & 7);
    gll16(Ab + (long)row * 256 + w * 16, AsB + (long)ci * 16);
  }
#pragma unroll
  for (int i = 0; i < 4; ++i) {
    int ci = i * 512 + tid;                  // 0..2047 16B-chunks (B, 128 rows)
    int row = ci >> 4;
    int w = (ci & 15) ^ (row & 7);
    gll16(Bb + (long)row * 256 + w * 16, BsB + (long)ci * 16);
  }
  __syncthreads();                            // vmcnt(0): tiles resident

  f32x4 acc[2][2];
#pragma unroll
  for (int mi = 0; mi < 2; ++mi)
#pragma unroll
    for (int ni = 0; ni < 2; ++ni) acc[mi][ni] = (f32x4)(0.f);

#pragma unroll
  for (int kk = 0; kk < 4; ++kk) {
    bf16x8 af[2], bfr[2];
#pragma unroll
    for (int mi = 0; mi < 2; ++mi) {
      int row = wr * 32 + mi * 16 + lr;
      int w = ((kk << 2) | g) ^ (row & 7);
      af[mi] = *(const bf16x8*)(AsB + row * 256 + w * 16);
    }
#pragma unroll
    for (int ni = 0; ni < 2; ++ni) {
      int row = wc * 32 + ni * 16 + lr;
      int w = ((kk << 2) | g) ^ (row & 7);
      bfr[ni] = *(const bf16x8*)(BsB + row * 256 + w * 16);
    }
#pragma unroll
    for (int mi = 0; mi < 2; ++mi)
#pragma unroll
      for (int ni = 0; ni < 2; ++ni)
        acc[mi][ni] = __builtin_amdgcn_mfma_f32_16x16x32_bf16(af[mi], bfr[ni], acc[mi][ni], 0, 0, 0);
  }

  if (PASS == 0) {
#pragma unroll
    for (int mi = 0; mi < 2; ++mi) {
#pragma unroll
      for (int r = 0; r < 4; ++r) {
        long row = brow + wr * 32 + mi * 16 + g * 4 + r;
        const float* urow = Ut + (long)(row / S_) * NPAD + bcol;
        float s = 0.f;
#pragma unroll
        for (int ni = 0; ni < 2; ++ni) {
          float u = urow[wc * 32 + ni * 16 + lr];
          s += __expf(acc[mi][ni][r] + u);
        }
#pragma unroll
        for (int off = 1; off < 16; off <<= 1) s += __shfl_xor(s, off);
        if (lr == 0) rsum4[wc][wr * 32 + mi * 16 + g * 4 + r] = s;
      }
    }
    __syncthreads();
    if (tid < 64)
      part[(long)bn * M_ + brow + tid] =
          rsum4[0][tid] + rsum4[1][tid] + rsum4[2][tid] + rsum4[3][tid];
  } else {
    if (bcol >= V_) return;                   // fully-OOB N panel (bn==157)
    const bool full = (bcol + 128 <= V_);
    __syncthreads();                           // As/Bs dead
#pragma unroll
    for (int mi = 0; mi < 2; ++mi) {
#pragma unroll
      for (int r = 0; r < 4; ++r) {
        int lrow = wr * 32 + mi * 16 + g * 4 + r;   // 0..63
        long row = brow + lrow;
        const float* urow = Ut + (long)(row / S_) * NPAD + bcol;
        float inv = 1.0f / rowsum[row];
        int key = ((lrow >> 2) & 3) << 2;           // = g<<2 (bank decorrelate)
#pragma unroll
        for (int ni = 0; ni < 2; ++ni) {
          int lcol = wc * 32 + ni * 16 + lr;
          lbuf[lrow * 128 + (lcol ^ key)] = __expf(acc[mi][ni][r] + urow[lcol]) * inv;
        }
      }
    }
    __syncthreads();
    if (full) {
#pragma unroll
      for (int it = 0; it < 4; ++it) {
        int idx = it * 512 + tid;             // 0..2047 f32x4 slots
        int lrow = idx >> 5, c4 = idx & 31;
        int key = ((lrow >> 2) & 3) << 2;
        f32x4 v = *(const f32x4*)(lbuf + lrow * 128 + ((c4 * 4) ^ key));
        __builtin_nontemporal_store(v,
            (f32x4*)(y + (brow + lrow) * (long)V_ + bcol + c4 * 4));
      }
    } else {
#pragma unroll
      for (int it = 0; it < 4; ++it) {
        int idx = it * 512 + tid;
        int lrow = idx >> 5, c4 = idx & 31;
        int key = ((lrow >> 2) & 3) << 2;
        const float* src = lbuf + lrow * 128 + ((c4 * 4) ^ key);
        long row = brow + lrow;
#pragma unroll
        for (int e = 0; e < 4; ++e) {
          int col = (int)bcol + c4 * 4 + e;
          if (col < V_) y[row * (long)V_ + col] = src[e];
        }
      }
    }
  }
}

__global__ void reduce_rows(const float* __restrict__ part, float* __restrict__ rowsum) {
  int m = blockIdx.x * 256 + threadIdx.x;            // grid 50 x 256
  if (m < M_) {
    float s = 0.f;
    for (int bn = 0; bn < NBN; ++bn) s += part[(long)bn * M_ + m];
    rowsum[m] = fmaxf(s, 1e-30f);
  }
}

// ---------------- launcher ----------------
extern "C" void kernel_launch(void* const* d_in, const int* in_sizes, int n_in,
                              void* d_out, int out_size, void* d_ws, size_t ws_size,
                              hipStream_t stream) {
  const int*   poi   = (const int*)d_in[0];
  // d_in[1] = lengths (all == S, unused)
  const float* ts    = (const float*)d_in[2];
  const float* loc   = (const float*)d_in[3];
  const int*   auser = (const int*)d_in[4];
  const float* embW  = (const float*)d_in[5];
  const float* userW = (const float*)d_in[6];
  const float* w_ih  = (const float*)d_in[7];
  const float* w_hh  = (const float*)d_in[8];
  const float* b_ih  = (const float*)d_in[9];
  const float* b_hh  = (const float*)d_in[10];
  const float* fcW   = (const float*)d_in[11];
  const float* fcb   = (const float*)d_in[12];

  float* out = (float*)d_out;
  char*  ws  = (char*)d_ws;
  __hip_bfloat16* Abf    = (__hip_bfloat16*)(ws + WS_A);
  __hip_bfloat16* w1b    = (__hip_bfloat16*)(ws + WS_FCW);
  float*          Ut     = (float*)(ws + WS_U);
  float*          rowsum = (float*)(ws + WS_RSUM);
  float*          wt_ih  = (float*)(ws + WS_WTIH);

  float* xp    = out + XP_OFF;     // scratch inside y region (overwritten by pass 1)
  float* hout  = out + HOUT_OFF;
  float* part  = out + PART_OFF;
  float* outpu = out + OUTPU_OFF;  // real output 1

  prep_wt<<<dim3(128), dim3(128), 0, stream>>>(w_ih, wt_ih);
  xproj_k<<<dim3(M_ / 16), dim3(128), 0, stream>>>(poi, embW, wt_ih, b_ih, b_hh, xp);
  fused_pre<<<dim3(64 + 158 + 632), dim3(256), 0, stream>>>(
      xp, w_hh, hout, fcW, w1b, auser, userW, fcb, Ut);
  attn_k<<<dim3(S_, B_), dim3(128), 0, stream>>>(ts, loc, hout, auser, userW, outpu, Abf);
  gemm_fc<0><<<dim3(NWG64), dim3(512), 0, stream>>>(Abf, w1b, Ut, nullptr, part, nullptr);
  reduce_rows<<<dim3(50), dim3(256), 0, stream>>>(part, rowsum);
  gemm_fc<1><<<dim3(NWG64), dim3(512), 0, stream>>>(Abf, w1b, Ut, rowsum, nullptr, out);
}